// Round 18
// baseline (232.523 us; speedup 1.0000x reference)
//
#include <hip/hip_runtime.h>

#define CIN 61
constexpr float EPS = 1e-5f;
constexpr double SCALE = 16777216.0;  // 2^24 fixed-point deterministic stat sums

using s16x8 = __attribute__((ext_vector_type(8))) short;
using fx4   = __attribute__((ext_vector_type(4))) float;

static __device__ __forceinline__ unsigned short f2bf(float f) {
  unsigned int u = __float_as_uint(f);
  u = (u + 0x7fffu + ((u >> 16) & 1u)) >> 16;
  return (unsigned short)u;
}
static __device__ __forceinline__ float bf2f(unsigned short h) {
  return __uint_as_float(((unsigned int)h) << 16);
}

__device__ __forceinline__ void stat_reduce(float val, float* red, long long* dst_ll) {
  int tid = threadIdx.x;
  red[tid] = val;
  __syncthreads();
  if (tid < 64) {
    float t = red[tid] + red[tid + 64] + red[tid + 128] + red[tid + 192];
    atomicAdd((unsigned long long*)&dst_ll[tid],
              (unsigned long long)(long long)((double)t * SCALE));
  }
  __syncthreads();
}

// ---- node pass, split by blockIdx: blocks <G do y-GEMV; blocks >=G do
//      s-GEMV + s-stats + dst hist/rank. One weight array per branch: no spill.
__global__ __launch_bounds__(256) void k_node(
    const float* __restrict__ x, const float* __restrict__ W1,
    const float* __restrict__ b1, const float* __restrict__ Ws,
    const float* __restrict__ bs, unsigned short* __restrict__ y,
    unsigned short* __restrict__ s_out, long long* __restrict__ stats, int N,
    const int* __restrict__ ei, unsigned int* __restrict__ hist,
    unsigned short* __restrict__ rank, int E, int G) {
  const int tid = threadIdx.x, lane = tid & 63, wv = tid >> 6;
  __shared__ float lrow[4][64];
  __shared__ float red[256];
  const int nq = N >> 2;
  if ((int)blockIdx.x < G) {
    // ---- y branch ----
    float w[64];
#pragma unroll
    for (int k = 0; k < 64; ++k) w[k] = (k < CIN) ? W1[k * 64 + lane] : 0.f;
    const float bv = b1[lane];
    for (int q = blockIdx.x; q < nq; q += G) {
      const int n = (q << 2) + wv;
      lrow[wv][lane] = (lane < CIN) ? x[(size_t)n * CIN + lane] : 0.f;
      __builtin_amdgcn_wave_barrier();
      float a0 = bv, a1 = 0.f, a2 = 0.f, a3 = 0.f;
      const float4* rr = (const float4*)&lrow[wv][0];
#pragma unroll
      for (int k4 = 0; k4 < 16; ++k4) {
        float4 v = rr[k4];
        a0 = fmaf(v.x, w[4 * k4 + 0], a0);
        a1 = fmaf(v.y, w[4 * k4 + 1], a1);
        a2 = fmaf(v.z, w[4 * k4 + 2], a2);
        a3 = fmaf(v.w, w[4 * k4 + 3], a3);
      }
      y[(size_t)n * 64 + lane] = f2bf((a0 + a1) + (a2 + a3));
      __builtin_amdgcn_wave_barrier();
    }
  } else {
    // ---- s branch (+ stats + hist/rank) ----
    const int b = blockIdx.x - G, nB = gridDim.x - G;
    float w[64];
#pragma unroll
    for (int k = 0; k < 64; ++k) w[k] = (k < CIN) ? Ws[k * 64 + lane] : 0.f;
    const float bv = bs[lane];
    float ssum = 0.f, ssq = 0.f;
    for (int q = b; q < nq; q += nB) {
      const int n = (q << 2) + wv;
      lrow[wv][lane] = (lane < CIN) ? x[(size_t)n * CIN + lane] : 0.f;
      __builtin_amdgcn_wave_barrier();
      float a0 = bv, a1 = 0.f, a2 = 0.f, a3 = 0.f;
      const float4* rr = (const float4*)&lrow[wv][0];
#pragma unroll
      for (int k4 = 0; k4 < 16; ++k4) {
        float4 v = rr[k4];
        a0 = fmaf(v.x, w[4 * k4 + 0], a0);
        a1 = fmaf(v.y, w[4 * k4 + 1], a1);
        a2 = fmaf(v.z, w[4 * k4 + 2], a2);
        a3 = fmaf(v.w, w[4 * k4 + 3], a3);
      }
      const float sacc = (a0 + a1) + (a2 + a3);
      s_out[(size_t)n * 64 + lane] = f2bf(sacc);
      ssum += sacc;
      ssq = fmaf(sacc, sacc, ssq);
      __builtin_amdgcn_wave_barrier();
    }
    stat_reduce(ssum, red, stats + 256);
    stat_reduce(ssq, red, stats + 320);
    for (int i = b * 256 + tid; i < E; i += nB * 256) {
      const int dst = ei[E + i];
      rank[i] = (unsigned short)atomicAdd(&hist[dst], 1u);
    }
  }
}

// ---- scan stage 1: per-1024-entry block sums ----
__global__ __launch_bounds__(256) void k_scan1(
    const unsigned int* __restrict__ hist, unsigned int* __restrict__ bsum) {
  const int tid = threadIdx.x, lane = tid & 63, wv = tid >> 6;
  const uint4 v = ((const uint4*)(hist + blockIdx.x * 1024))[tid];
  unsigned int s = v.x + v.y + v.z + v.w;
#pragma unroll
  for (int off = 1; off < 64; off <<= 1) s += __shfl_xor(s, off);
  __shared__ unsigned int wsum[4];
  if (lane == 0) wsum[wv] = s;
  __syncthreads();
  if (tid == 0) bsum[blockIdx.x] = wsum[0] + wsum[1] + wsum[2] + wsum[3];
}

// ---- scan stage 2 (fused): block-offset from bsum + cursor0 ----
__global__ __launch_bounds__(256) void k_scan3(
    const unsigned int* __restrict__ hist, const unsigned int* __restrict__ bsum,
    unsigned int* __restrict__ cursor0) {
  const int tid = threadIdx.x, lane = tid & 63, wv = tid >> 6;
  __shared__ unsigned int s_boff;
  if (tid < 64) {
    unsigned int v = (tid < blockIdx.x) ? bsum[tid] : 0u;  // gridDim <= 64
#pragma unroll
    for (int off = 1; off < 64; off <<= 1) v += __shfl_xor(v, off);
    if (tid == 0) s_boff = v;
  }
  const uint4 v = ((const uint4*)(hist + blockIdx.x * 1024))[tid];
  const unsigned int s = v.x + v.y + v.z + v.w;
  unsigned int incl = s;
#pragma unroll
  for (int off = 1; off < 64; off <<= 1) {
    unsigned int u = __shfl_up(incl, off);
    if (lane >= off) incl += u;
  }
  __shared__ unsigned int wtot[4];
  if (lane == 63) wtot[wv] = incl;
  __syncthreads();
  unsigned int wb = s_boff;
#pragma unroll
  for (int k = 0; k < 4; ++k) wb += (k < wv) ? wtot[k] : 0u;
  const unsigned int ex = wb + incl - s;
  uint4 o;
  o.x = ex; o.y = ex + v.x; o.z = o.y + v.y; o.w = o.z + v.z;
  ((uint4*)(cursor0 + blockIdx.x * 1024))[tid] = o;
}

// ---- edge pass 1: 4 batches of 8 edges per wave iteration; t1 stats +
//      full bf16 t1 row scatter-stored NON-TEMPORALLY at its dst-sorted slot
//      (bypasses L2: avoids dirty cross-XCD lines that k_edge2 must demand-
//      writeback when reading) ----
__global__ __launch_bounds__(256) void k_edge1(
    const int* __restrict__ ei, const float* __restrict__ pos,
    const unsigned short* __restrict__ y, const float* __restrict__ W1,
    const unsigned int* __restrict__ cursor0, const unsigned short* __restrict__ rank,
    unsigned short* __restrict__ t1S, long long* __restrict__ stats, int E) {
  const int tid = threadIdx.x, lane = tid & 63, wv = tid >> 6;
  const int g8 = lane >> 3, c8 = lane & 7;
  float wp[3][8];
#pragma unroll
  for (int d = 0; d < 3; ++d)
#pragma unroll
    for (int i = 0; i < 8; ++i) wp[d][i] = W1[(61 + d) * 64 + 8 * c8 + i];
  float ssum[8] = {0.f, 0.f, 0.f, 0.f, 0.f, 0.f, 0.f, 0.f};
  float ssq[8]  = {0.f, 0.f, 0.f, 0.f, 0.f, 0.f, 0.f, 0.f};
  const int ngrp = E >> 3;
  const int nw = gridDim.x * 4;
  for (int q = blockIdx.x * 4 + wv; q < ngrp; q += 4 * nw) {
    const int qB = q + nw, qC = q + 2 * nw, qD = q + 3 * nw;
    const bool hB = qB < ngrp, hC = qC < ngrp, hD = qD < ngrp;
    const int eA = (q << 3) + g8;
    const int eB = hB ? (qB << 3) + g8 : eA;
    const int eC = hC ? (qC << 3) + g8 : eA;
    const int eD = hD ? (qD << 3) + g8 : eA;
    const int srcA = ei[eA], dstA = ei[E + eA];
    const int srcB = ei[eB], dstB = ei[E + eB];
    const int srcC = ei[eC], dstC = ei[E + eC];
    const int srcD = ei[eD], dstD = ei[E + eD];
    float pvA = 0.f, pvB = 0.f, pvC = 0.f, pvD = 0.f;
    if (c8 < 3) {
      pvA = pos[srcA * 3 + c8] - pos[dstA * 3 + c8];
      pvB = pos[srcB * 3 + c8] - pos[dstB * 3 + c8];
      pvC = pos[srcC * 3 + c8] - pos[dstC * 3 + c8];
      pvD = pos[srcD * 3 + c8] - pos[dstD * 3 + c8];
    }
    const s16x8 yA = *(const s16x8*)(y + (unsigned)srcA * 64u + 8u * (unsigned)c8);
    const s16x8 yB = *(const s16x8*)(y + (unsigned)srcB * 64u + 8u * (unsigned)c8);
    const s16x8 yC = *(const s16x8*)(y + (unsigned)srcC * 64u + 8u * (unsigned)c8);
    const s16x8 yD = *(const s16x8*)(y + (unsigned)srcD * 64u + 8u * (unsigned)c8);
    unsigned offA = 0, offB = 0, offC = 0, offD = 0;
    if (c8 == 0) {
      offA = cursor0[dstA] + rank[eA];
      offB = cursor0[dstB] + rank[eB];
      offC = cursor0[dstC] + rank[eC];
      offD = cursor0[dstD] + rank[eD];
    }
#define EDGE1_BODY(PV, YV, OFFV)                                                \
    {                                                                           \
      const float p0 = __shfl(PV, g8 * 8 + 0);                                  \
      const float p1 = __shfl(PV, g8 * 8 + 1);                                  \
      const float p2 = __shfl(PV, g8 * 8 + 2);                                  \
      const unsigned off = __shfl(OFFV, g8 * 8 + 0);                            \
      union { s16x8 v; unsigned short s[8]; } tb;                               \
      _Pragma("unroll")                                                         \
      for (int i = 0; i < 8; ++i) {                                             \
        float v = bf2f((unsigned short)YV[i]);                                  \
        v = fmaf(p0, wp[0][i], v);                                              \
        v = fmaf(p1, wp[1][i], v);                                              \
        v = fmaf(p2, wp[2][i], v);                                              \
        v = fmaxf(v, 0.f);                                                      \
        ssum[i] += v;                                                           \
        ssq[i] = fmaf(v, v, ssq[i]);                                            \
        tb.s[i] = f2bf(v);                                                      \
      }                                                                         \
      __builtin_nontemporal_store(tb.v, (s16x8*)(t1S + (size_t)off * 64 + 8 * c8)); \
    }
    EDGE1_BODY(pvA, yA, offA)
    if (hB) EDGE1_BODY(pvB, yB, offB)
    if (hC) EDGE1_BODY(pvC, yC, offC)
    if (hD) EDGE1_BODY(pvD, yD, offD)
#undef EDGE1_BODY
  }
#pragma unroll
  for (int i = 0; i < 8; ++i) {
    ssum[i] += __shfl_xor(ssum[i], 8);
    ssum[i] += __shfl_xor(ssum[i], 16);
    ssum[i] += __shfl_xor(ssum[i], 32);
    ssq[i] += __shfl_xor(ssq[i], 8);
    ssq[i] += __shfl_xor(ssq[i], 16);
    ssq[i] += __shfl_xor(ssq[i], 32);
  }
  __shared__ float sred[2][64];
  if (tid < 128) ((float*)sred)[tid] = 0.f;
  __syncthreads();
  if (g8 == 0) {
#pragma unroll
    for (int i = 0; i < 8; ++i) {
      atomicAdd(&sred[0][8 * c8 + i], ssum[i]);
      atomicAdd(&sred[1][8 * c8 + i], ssq[i]);
    }
  }
  __syncthreads();
  if (tid < 64) {
    atomicAdd((unsigned long long*)&stats[0 + tid],
              (unsigned long long)(long long)((double)sred[0][tid] * SCALE));
    atomicAdd((unsigned long long*)&stats[64 + tid],
              (unsigned long long)(long long)((double)sred[1][tid] * SCALE));
  }
}

// ---- BN1 coef + fold into W2 -> pre-permuted bFpack + biasF ----
__global__ void k_coefA(const long long* __restrict__ stats,
                        const float* __restrict__ g1, const float* __restrict__ be1,
                        const float* __restrict__ W2, const float* __restrict__ b2,
                        unsigned short* __restrict__ bFpack,
                        float* __restrict__ biasF, double invE) {
  const int c = threadIdx.x;  // 64 threads
  __shared__ float a1s[64], c1s[64], b2sh[64];
  double m = (double)stats[c] * invE;
  double v = (double)stats[64 + c] * invE - m * m;
  float a = g1[c] * rsqrtf((float)v + EPS);
  a1s[c] = a;
  c1s[c] = fmaf(-(float)m, a, be1[c]);
  __syncthreads();
  float acc = b2[c];
  for (int k = 0; k < 64; ++k) acc = fmaf(c1s[k], W2[k * 64 + c], acc);
  b2sh[c] = acc;
  const int lg = c >> 4, l15 = c & 15;
#pragma unroll
  for (int t = 0; t < 4; ++t)
#pragma unroll
    for (int s = 0; s < 2; ++s)
#pragma unroll
      for (int i = 0; i < 8; ++i) {
        const int k = s * 32 + lg * 8 + i;
        bFpack[c * 64 + t * 16 + s * 8 + i] = f2bf(a1s[k] * W2[k * 64 + l15 + 16 * t]);
      }
  __syncthreads();
  float4 bf;
  bf.x = b2sh[l15]; bf.y = b2sh[l15 + 16]; bf.z = b2sh[l15 + 32]; bf.w = b2sh[l15 + 48];
  ((float4*)biasF)[c] = bf;
}

// ---- edge pass 2 (node-centric, zero atomics) + fused raw-max stats;
//      t1S read via NON-TEMPORAL loads (single-use stream) ----
__global__ __launch_bounds__(256) void k_edge2(
    const unsigned short* __restrict__ t1S, const unsigned int* __restrict__ cursor0,
    const unsigned short* __restrict__ bFpack, const float* __restrict__ biasF,
    long long* __restrict__ stats, float* __restrict__ agg, int N) {
  const int tid = threadIdx.x, lane = tid & 63, wv = tid >> 6;
  const int l15 = lane & 15, lg = lane >> 4;
  s16x8 bF[4][2];
  {
    const s16x8* bfp = (const s16x8*)(bFpack + (size_t)lane * 64);
#pragma unroll
    for (int t = 0; t < 4; ++t)
#pragma unroll
      for (int s = 0; s < 2; ++s) bF[t][s] = bfp[t * 2 + s];
  }
  float bias[4];
  {
    const float4 bv = ((const float4*)biasF)[lane];
    bias[0] = bv.x; bias[1] = bv.y; bias[2] = bv.z; bias[3] = bv.w;
  }
  float ssum[4] = {0.f, 0.f, 0.f, 0.f}, ssq[4] = {0.f, 0.f, 0.f, 0.f};
  float msum[4] = {0.f, 0.f, 0.f, 0.f}, msq[4] = {0.f, 0.f, 0.f, 0.f};
  float kc = 0.f;
  const int nw = gridDim.x * 4;
  for (int d = blockIdx.x * 4 + wv; d < N; d += nw) {
    const unsigned lo = cursor0[d];
    const unsigned deg = cursor0[d + 1] - lo;
    if (deg == 0) continue;  // wave-uniform; agg never read for empty nodes
    kc += 1.f;
    const unsigned last = lo + deg - 1u;
    float mx[4] = {0.f, 0.f, 0.f, 0.f};
    for (unsigned base = 0; base < deg; base += 16u) {
      unsigned gr = lo + base + (unsigned)l15;
      if (gr > last) gr = last;  // clamp: duplicates of a real row (max-safe)
      const unsigned short* ar = t1S + (size_t)gr * 64 + (unsigned)(lg * 8);
      const s16x8 aF0 = __builtin_nontemporal_load((const s16x8*)ar);
      const s16x8 aF1 = __builtin_nontemporal_load((const s16x8*)(ar + 32));
      fx4 acc[4];
#pragma unroll
      for (int t = 0; t < 4; ++t) {
        acc[t][0] = bias[t]; acc[t][1] = bias[t];
        acc[t][2] = bias[t]; acc[t][3] = bias[t];
      }
#pragma unroll
      for (int t = 0; t < 4; ++t) {
        acc[t] = __builtin_amdgcn_mfma_f32_16x16x32_bf16(aF0, bF[t][0], acc[t], 0, 0, 0);
        acc[t] = __builtin_amdgcn_mfma_f32_16x16x32_bf16(aF1, bF[t][1], acc[t], 0, 0, 0);
      }
      const int rem = (int)(deg - base);  // valid rows this tile (may exceed 16)
#pragma unroll
      for (int t = 0; t < 4; ++t)
#pragma unroll
        for (int j = 0; j < 4; ++j) {
          const float v = fmaxf(acc[t][j], 0.f);
          mx[t] = fmaxf(mx[t], v);  // duplicate rows repeat a real value: safe
          const int row = lg * 4 + j;
          if (row < rem) {  // masked stats: each edge row counted exactly once
            ssum[t] += v;
            ssq[t] = fmaf(v, v, ssq[t]);
          }
        }
    }
#pragma unroll
    for (int t = 0; t < 4; ++t) {
      mx[t] = fmaxf(mx[t], __shfl_xor(mx[t], 16));
      mx[t] = fmaxf(mx[t], __shfl_xor(mx[t], 32));
    }
    if (lg == 0) {
#pragma unroll
      for (int t = 0; t < 4; ++t) {
        msum[t] += mx[t];
        msq[t] = fmaf(mx[t], mx[t], msq[t]);
      }
    }
    const float val = (lg == 0) ? mx[0] : (lg == 1) ? mx[1] : (lg == 2) ? mx[2] : mx[3];
    __builtin_nontemporal_store(val, agg + (size_t)d * 64 + (unsigned)(l15 + 16 * lg));
  }
#pragma unroll
  for (int t = 0; t < 4; ++t) {
    ssum[t] += __shfl_xor(ssum[t], 16); ssum[t] += __shfl_xor(ssum[t], 32);
    ssq[t]  += __shfl_xor(ssq[t], 16);  ssq[t]  += __shfl_xor(ssq[t], 32);
  }
  __shared__ float sred[4][64];
  __shared__ float kcs;
  if (tid < 256) ((float*)sred)[tid] = 0.f;
  if (tid == 0) kcs = 0.f;
  __syncthreads();
  if (lg == 0) {
#pragma unroll
    for (int t = 0; t < 4; ++t) {
      atomicAdd(&sred[0][l15 + 16 * t], ssum[t]);
      atomicAdd(&sred[1][l15 + 16 * t], ssq[t]);
      atomicAdd(&sred[2][l15 + 16 * t], msum[t]);
      atomicAdd(&sred[3][l15 + 16 * t], msq[t]);
    }
  }
  if (lane == 0) atomicAdd(&kcs, kc);
  __syncthreads();
  if (tid < 64) {
    atomicAdd((unsigned long long*)&stats[128 + tid],
              (unsigned long long)(long long)((double)sred[0][tid] * SCALE));
    atomicAdd((unsigned long long*)&stats[192 + tid],
              (unsigned long long)(long long)((double)sred[1][tid] * SCALE));
    atomicAdd((unsigned long long*)&stats[384 + tid],
              (unsigned long long)(long long)((double)sred[2][tid] * SCALE));
    atomicAdd((unsigned long long*)&stats[448 + tid],
              (unsigned long long)(long long)((double)sred[3][tid] * SCALE));
  }
  if (tid == 0)
    atomicAdd((unsigned long long*)&stats[512],
              (unsigned long long)(long long)((double)kcs * SCALE));
}

// ---- remaining BN coefs composed for the final pass ----
__global__ void k_coefB(const long long* __restrict__ stats,
                        const float* __restrict__ g2, const float* __restrict__ be2,
                        const float* __restrict__ gs, const float* __restrict__ bes,
                        const float* __restrict__ gf, const float* __restrict__ bef,
                        float* __restrict__ coef, double invE, double invN, int N) {
  const int c = threadIdx.x;
  double m2 = (double)stats[128 + c] * invE;
  double v2 = (double)stats[192 + c] * invE - m2 * m2;
  float a2 = g2[c] * rsqrtf((float)v2 + EPS);
  float c2 = fmaf(-(float)m2, a2, be2[c]);
  double mS = (double)stats[256 + c] * invN;
  double vS = (double)stats[320 + c] * invN - mS * mS;
  float aS = gs[c] * rsqrtf((float)vS + EPS);
  float cS = fmaf(-(float)mS, aS, bes[c]);
  double su = (double)stats[384 + c] / SCALE;
  double qu = (double)stats[448 + c] / SCALE;
  double K  = (double)stats[512] / SCALE;
  double sv = (double)a2 * su + (double)c2 * K;
  double qv = (double)a2 * a2 * qu + 2.0 * a2 * c2 * su + (double)c2 * c2 * K;
  double mv = sv / N;
  double vv = qv / N - mv * mv;
  float aF = gf[c] * rsqrtf((float)vv + EPS);
  float cF = fmaf(-(float)mv, aF, bef[c]);
  coef[c]       = aF * a2;
  coef[64 + c]  = fmaf(aF, c2, cF);
  coef[128 + c] = cF;
  coef[192 + c] = aS;
  coef[256 + c] = cS;
}

__global__ __launch_bounds__(256) void k_final(
    const float* __restrict__ agg, const unsigned int* __restrict__ hist,
    const unsigned short* __restrict__ sbuf, const float* __restrict__ coef,
    float* __restrict__ out, int total) {
  int i = blockIdx.x * 256 + threadIdx.x;
  if (i >= total) return;
  const int c = i & 63;
  float base;
  if (hist[i >> 6])
    base = fmaf(coef[c], agg[i], coef[64 + c]);
  else
    base = coef[128 + c];
  const float sv = fmaf(coef[192 + c], bf2f(sbuf[i]), coef[256 + c]);
  out[i] = fmaxf(base + sv, 0.f);
}

extern "C" void kernel_launch(void* const* d_in, const int* in_sizes, int n_in,
                              void* d_out, int out_size, void* d_ws, size_t ws_size,
                              hipStream_t stream) {
  const float* x   = (const float*)d_in[0];
  const float* pos = (const float*)d_in[1];
  const int*   ei  = (const int*)d_in[2];
  const float* W1  = (const float*)d_in[3];
  const float* b1  = (const float*)d_in[4];
  const float* g1  = (const float*)d_in[5];
  const float* be1 = (const float*)d_in[6];
  const float* W2  = (const float*)d_in[7];
  const float* b2  = (const float*)d_in[8];
  const float* g2  = (const float*)d_in[9];
  const float* be2 = (const float*)d_in[10];
  const float* Ws  = (const float*)d_in[11];
  const float* bs  = (const float*)d_in[12];
  const float* gs  = (const float*)d_in[13];
  const float* bes = (const float*)d_in[14];
  const float* gf  = (const float*)d_in[15];
  const float* bef = (const float*)d_in[16];
  const int N = in_sizes[0] / CIN;   // 50000
  const int E = in_sizes[2] / 2;     // 800000

  char* ws = (char*)d_ws;
  const size_t o_stats = 0;                            // 513 ll -> pad 4608
  const size_t o_bsum  = 4608;                         // 49 u32 -> page ends 8192
  const size_t o_hist  = 8192;                         // 50176 u32 (zeroed)
  const size_t zeroEnd = o_hist + 200704;              // memset ONLY stats+hist
  const size_t o_agg   = zeroEnd;                      // N*256 (f32; no init needed)
  const size_t o_curs0 = o_agg + (size_t)N * 256;      // 50176 u32
  const size_t o_coef  = o_curs0 + 200704;             // 4096
  const size_t o_frag  = o_coef + 4096;                // bFpack 8192 | biasF 1024
  const size_t o_rank  = o_frag + 12288;               // E*2
  const size_t o_ybuf  = o_rank + (size_t)E * 2;       // N*128
  const size_t o_sbuf  = o_ybuf + (size_t)N * 128;     // N*128
  const size_t o_t1S   = o_sbuf + (size_t)N * 128;     // E*128

  long long* stats      = (long long*)(ws + o_stats);
  unsigned int* bsum    = (unsigned int*)(ws + o_bsum);
  unsigned int* hist    = (unsigned int*)(ws + o_hist);
  float* agg            = (float*)(ws + o_agg);
  unsigned int* cursor0 = (unsigned int*)(ws + o_curs0);
  float* coef           = (float*)(ws + o_coef);
  unsigned short* bFpack= (unsigned short*)(ws + o_frag);
  float* biasF          = (float*)(ws + o_frag + 8192);
  unsigned short* rank  = (unsigned short*)(ws + o_rank);
  unsigned short* ybuf  = (unsigned short*)(ws + o_ybuf);
  unsigned short* sbuf  = (unsigned short*)(ws + o_sbuf);
  unsigned short* t1S   = (unsigned short*)(ws + o_t1S);

  const double invE = 1.0 / (SCALE * (double)E);
  const double invN = 1.0 / (SCALE * (double)N);
  const int total = N * 64;
  const int nScanBlk = 49;  // ceil(50176/1024)

  hipMemsetAsync(d_ws, 0, zeroEnd, stream);

  hipLaunchKernelGGL(k_node, dim3(1024), dim3(256), 0, stream,
                     x, W1, b1, Ws, bs, ybuf, sbuf, stats, N, ei, hist, rank, E, 448);
  hipLaunchKernelGGL(k_scan1, dim3(nScanBlk), dim3(256), 0, stream, hist, bsum);
  hipLaunchKernelGGL(k_scan3, dim3(nScanBlk), dim3(256), 0, stream,
                     hist, bsum, cursor0);
  hipLaunchKernelGGL(k_edge1, dim3(2048), dim3(256), 0, stream,
                     ei, pos, ybuf, W1, cursor0, rank, t1S, stats, E);
  hipLaunchKernelGGL(k_coefA, dim3(1), dim3(64), 0, stream,
                     stats, g1, be1, W2, b2, bFpack, biasF, invE);
  hipLaunchKernelGGL(k_edge2, dim3(2048), dim3(256), 0, stream,
                     t1S, cursor0, bFpack, biasF, stats, agg, N);
  hipLaunchKernelGGL(k_coefB, dim3(1), dim3(64), 0, stream,
                     stats, g2, be2, gs, bes, gf, bef, coef, invE, invN, N);
  hipLaunchKernelGGL(k_final, dim3((total + 255) / 256), dim3(256), 0, stream,
                     agg, hist, sbuf, coef, (float*)d_out, total);
}

// Round 19
// 226.571 us; speedup vs baseline: 1.0263x; 1.0263x over previous
//
#include <hip/hip_runtime.h>

#define CIN 61
constexpr float EPS = 1e-5f;
constexpr double SCALE = 16777216.0;  // 2^24 fixed-point deterministic stat sums

using s16x8 = __attribute__((ext_vector_type(8))) short;
using fx4   = __attribute__((ext_vector_type(4))) float;

static __device__ __forceinline__ unsigned short f2bf(float f) {
  unsigned int u = __float_as_uint(f);
  u = (u + 0x7fffu + ((u >> 16) & 1u)) >> 16;
  return (unsigned short)u;
}
static __device__ __forceinline__ float bf2f(unsigned short h) {
  return __uint_as_float(((unsigned int)h) << 16);
}

__device__ __forceinline__ void stat_reduce(float val, float* red, long long* dst_ll) {
  int tid = threadIdx.x;
  red[tid] = val;
  __syncthreads();
  if (tid < 64) {
    float t = red[tid] + red[tid + 64] + red[tid + 128] + red[tid + 192];
    atomicAdd((unsigned long long*)&dst_ll[tid],
              (unsigned long long)(long long)((double)t * SCALE));
  }
  __syncthreads();
}

// ---- node pass, split by blockIdx: blocks <G do y-GEMV; blocks >=G do
//      s-GEMV + s-stats + dst hist/rank. One weight array per branch: no spill.
__global__ __launch_bounds__(256) void k_node(
    const float* __restrict__ x, const float* __restrict__ W1,
    const float* __restrict__ b1, const float* __restrict__ Ws,
    const float* __restrict__ bs, unsigned short* __restrict__ y,
    unsigned short* __restrict__ s_out, long long* __restrict__ stats, int N,
    const int* __restrict__ ei, unsigned int* __restrict__ hist,
    unsigned short* __restrict__ rank, int E, int G) {
  const int tid = threadIdx.x, lane = tid & 63, wv = tid >> 6;
  __shared__ float lrow[4][64];
  __shared__ float red[256];
  const int nq = N >> 2;
  if ((int)blockIdx.x < G) {
    // ---- y branch ----
    float w[64];
#pragma unroll
    for (int k = 0; k < 64; ++k) w[k] = (k < CIN) ? W1[k * 64 + lane] : 0.f;
    const float bv = b1[lane];
    for (int q = blockIdx.x; q < nq; q += G) {
      const int n = (q << 2) + wv;
      lrow[wv][lane] = (lane < CIN) ? x[(size_t)n * CIN + lane] : 0.f;
      __builtin_amdgcn_wave_barrier();
      float a0 = bv, a1 = 0.f, a2 = 0.f, a3 = 0.f;
      const float4* rr = (const float4*)&lrow[wv][0];
#pragma unroll
      for (int k4 = 0; k4 < 16; ++k4) {
        float4 v = rr[k4];
        a0 = fmaf(v.x, w[4 * k4 + 0], a0);
        a1 = fmaf(v.y, w[4 * k4 + 1], a1);
        a2 = fmaf(v.z, w[4 * k4 + 2], a2);
        a3 = fmaf(v.w, w[4 * k4 + 3], a3);
      }
      y[(size_t)n * 64 + lane] = f2bf((a0 + a1) + (a2 + a3));
      __builtin_amdgcn_wave_barrier();
    }
  } else {
    // ---- s branch (+ stats + hist/rank) ----
    const int b = blockIdx.x - G, nB = gridDim.x - G;
    float w[64];
#pragma unroll
    for (int k = 0; k < 64; ++k) w[k] = (k < CIN) ? Ws[k * 64 + lane] : 0.f;
    const float bv = bs[lane];
    float ssum = 0.f, ssq = 0.f;
    for (int q = b; q < nq; q += nB) {
      const int n = (q << 2) + wv;
      lrow[wv][lane] = (lane < CIN) ? x[(size_t)n * CIN + lane] : 0.f;
      __builtin_amdgcn_wave_barrier();
      float a0 = bv, a1 = 0.f, a2 = 0.f, a3 = 0.f;
      const float4* rr = (const float4*)&lrow[wv][0];
#pragma unroll
      for (int k4 = 0; k4 < 16; ++k4) {
        float4 v = rr[k4];
        a0 = fmaf(v.x, w[4 * k4 + 0], a0);
        a1 = fmaf(v.y, w[4 * k4 + 1], a1);
        a2 = fmaf(v.z, w[4 * k4 + 2], a2);
        a3 = fmaf(v.w, w[4 * k4 + 3], a3);
      }
      const float sacc = (a0 + a1) + (a2 + a3);
      s_out[(size_t)n * 64 + lane] = f2bf(sacc);
      ssum += sacc;
      ssq = fmaf(sacc, sacc, ssq);
      __builtin_amdgcn_wave_barrier();
    }
    stat_reduce(ssum, red, stats + 256);
    stat_reduce(ssq, red, stats + 320);
    for (int i = b * 256 + tid; i < E; i += nB * 256) {
      const int dst = ei[E + i];
      rank[i] = (unsigned short)atomicAdd(&hist[dst], 1u);
    }
  }
}

// ---- scan stage 1: per-1024-entry block sums ----
__global__ __launch_bounds__(256) void k_scan1(
    const unsigned int* __restrict__ hist, unsigned int* __restrict__ bsum) {
  const int tid = threadIdx.x, lane = tid & 63, wv = tid >> 6;
  const uint4 v = ((const uint4*)(hist + blockIdx.x * 1024))[tid];
  unsigned int s = v.x + v.y + v.z + v.w;
#pragma unroll
  for (int off = 1; off < 64; off <<= 1) s += __shfl_xor(s, off);
  __shared__ unsigned int wsum[4];
  if (lane == 0) wsum[wv] = s;
  __syncthreads();
  if (tid == 0) bsum[blockIdx.x] = wsum[0] + wsum[1] + wsum[2] + wsum[3];
}

// ---- scan stage 2 (fused): block-offset from bsum + cursor0 ----
__global__ __launch_bounds__(256) void k_scan3(
    const unsigned int* __restrict__ hist, const unsigned int* __restrict__ bsum,
    unsigned int* __restrict__ cursor0) {
  const int tid = threadIdx.x, lane = tid & 63, wv = tid >> 6;
  __shared__ unsigned int s_boff;
  if (tid < 64) {
    unsigned int v = (tid < blockIdx.x) ? bsum[tid] : 0u;  // gridDim <= 64
#pragma unroll
    for (int off = 1; off < 64; off <<= 1) v += __shfl_xor(v, off);
    if (tid == 0) s_boff = v;
  }
  const uint4 v = ((const uint4*)(hist + blockIdx.x * 1024))[tid];
  const unsigned int s = v.x + v.y + v.z + v.w;
  unsigned int incl = s;
#pragma unroll
  for (int off = 1; off < 64; off <<= 1) {
    unsigned int u = __shfl_up(incl, off);
    if (lane >= off) incl += u;
  }
  __shared__ unsigned int wtot[4];
  if (lane == 63) wtot[wv] = incl;
  __syncthreads();
  unsigned int wb = s_boff;
#pragma unroll
  for (int k = 0; k < 4; ++k) wb += (k < wv) ? wtot[k] : 0u;
  const unsigned int ex = wb + incl - s;
  uint4 o;
  o.x = ex; o.y = ex + v.x; o.z = o.y + v.y; o.w = o.z + v.z;
  ((uint4*)(cursor0 + blockIdx.x * 1024))[tid] = o;
}

// ---- edge pass 1: 4 batches of 8 edges per wave iteration; t1 stats +
//      full bf16 t1 row scatter-stored at its dst-sorted slot ----
__global__ __launch_bounds__(256) void k_edge1(
    const int* __restrict__ ei, const float* __restrict__ pos,
    const unsigned short* __restrict__ y, const float* __restrict__ W1,
    const unsigned int* __restrict__ cursor0, const unsigned short* __restrict__ rank,
    unsigned short* __restrict__ t1S, long long* __restrict__ stats, int E) {
  const int tid = threadIdx.x, lane = tid & 63, wv = tid >> 6;
  const int g8 = lane >> 3, c8 = lane & 7;
  float wp[3][8];
#pragma unroll
  for (int d = 0; d < 3; ++d)
#pragma unroll
    for (int i = 0; i < 8; ++i) wp[d][i] = W1[(61 + d) * 64 + 8 * c8 + i];
  float ssum[8] = {0.f, 0.f, 0.f, 0.f, 0.f, 0.f, 0.f, 0.f};
  float ssq[8]  = {0.f, 0.f, 0.f, 0.f, 0.f, 0.f, 0.f, 0.f};
  const int ngrp = E >> 3;
  const int nw = gridDim.x * 4;
  for (int q = blockIdx.x * 4 + wv; q < ngrp; q += 4 * nw) {
    const int qB = q + nw, qC = q + 2 * nw, qD = q + 3 * nw;
    const bool hB = qB < ngrp, hC = qC < ngrp, hD = qD < ngrp;
    const int eA = (q << 3) + g8;
    const int eB = hB ? (qB << 3) + g8 : eA;
    const int eC = hC ? (qC << 3) + g8 : eA;
    const int eD = hD ? (qD << 3) + g8 : eA;
    const int srcA = ei[eA], dstA = ei[E + eA];
    const int srcB = ei[eB], dstB = ei[E + eB];
    const int srcC = ei[eC], dstC = ei[E + eC];
    const int srcD = ei[eD], dstD = ei[E + eD];
    float pvA = 0.f, pvB = 0.f, pvC = 0.f, pvD = 0.f;
    if (c8 < 3) {
      pvA = pos[srcA * 3 + c8] - pos[dstA * 3 + c8];
      pvB = pos[srcB * 3 + c8] - pos[dstB * 3 + c8];
      pvC = pos[srcC * 3 + c8] - pos[dstC * 3 + c8];
      pvD = pos[srcD * 3 + c8] - pos[dstD * 3 + c8];
    }
    const s16x8 yA = *(const s16x8*)(y + (unsigned)srcA * 64u + 8u * (unsigned)c8);
    const s16x8 yB = *(const s16x8*)(y + (unsigned)srcB * 64u + 8u * (unsigned)c8);
    const s16x8 yC = *(const s16x8*)(y + (unsigned)srcC * 64u + 8u * (unsigned)c8);
    const s16x8 yD = *(const s16x8*)(y + (unsigned)srcD * 64u + 8u * (unsigned)c8);
    unsigned offA = 0, offB = 0, offC = 0, offD = 0;
    if (c8 == 0) {
      offA = cursor0[dstA] + rank[eA];
      offB = cursor0[dstB] + rank[eB];
      offC = cursor0[dstC] + rank[eC];
      offD = cursor0[dstD] + rank[eD];
    }
#define EDGE1_BODY(PV, YV, OFFV)                                                \
    {                                                                           \
      const float p0 = __shfl(PV, g8 * 8 + 0);                                  \
      const float p1 = __shfl(PV, g8 * 8 + 1);                                  \
      const float p2 = __shfl(PV, g8 * 8 + 2);                                  \
      const unsigned off = __shfl(OFFV, g8 * 8 + 0);                            \
      union { s16x8 v; unsigned short s[8]; } tb;                               \
      _Pragma("unroll")                                                         \
      for (int i = 0; i < 8; ++i) {                                             \
        float v = bf2f((unsigned short)YV[i]);                                  \
        v = fmaf(p0, wp[0][i], v);                                              \
        v = fmaf(p1, wp[1][i], v);                                              \
        v = fmaf(p2, wp[2][i], v);                                              \
        v = fmaxf(v, 0.f);                                                      \
        ssum[i] += v;                                                           \
        ssq[i] = fmaf(v, v, ssq[i]);                                            \
        tb.s[i] = f2bf(v);                                                      \
      }                                                                         \
      *(s16x8*)(t1S + (size_t)off * 64 + 8 * c8) = tb.v;                        \
    }
    EDGE1_BODY(pvA, yA, offA)
    if (hB) EDGE1_BODY(pvB, yB, offB)
    if (hC) EDGE1_BODY(pvC, yC, offC)
    if (hD) EDGE1_BODY(pvD, yD, offD)
#undef EDGE1_BODY
  }
#pragma unroll
  for (int i = 0; i < 8; ++i) {
    ssum[i] += __shfl_xor(ssum[i], 8);
    ssum[i] += __shfl_xor(ssum[i], 16);
    ssum[i] += __shfl_xor(ssum[i], 32);
    ssq[i] += __shfl_xor(ssq[i], 8);
    ssq[i] += __shfl_xor(ssq[i], 16);
    ssq[i] += __shfl_xor(ssq[i], 32);
  }
  __shared__ float sred[2][64];
  if (tid < 128) ((float*)sred)[tid] = 0.f;
  __syncthreads();
  if (g8 == 0) {
#pragma unroll
    for (int i = 0; i < 8; ++i) {
      atomicAdd(&sred[0][8 * c8 + i], ssum[i]);
      atomicAdd(&sred[1][8 * c8 + i], ssq[i]);
    }
  }
  __syncthreads();
  if (tid < 64) {
    atomicAdd((unsigned long long*)&stats[0 + tid],
              (unsigned long long)(long long)((double)sred[0][tid] * SCALE));
    atomicAdd((unsigned long long*)&stats[64 + tid],
              (unsigned long long)(long long)((double)sred[1][tid] * SCALE));
  }
}

// ---- BN1 coef + fold into W2 -> pre-permuted bFpack + biasF ----
__global__ void k_coefA(const long long* __restrict__ stats,
                        const float* __restrict__ g1, const float* __restrict__ be1,
                        const float* __restrict__ W2, const float* __restrict__ b2,
                        unsigned short* __restrict__ bFpack,
                        float* __restrict__ biasF, double invE) {
  const int c = threadIdx.x;  // 64 threads
  __shared__ float a1s[64], c1s[64], b2sh[64];
  double m = (double)stats[c] * invE;
  double v = (double)stats[64 + c] * invE - m * m;
  float a = g1[c] * rsqrtf((float)v + EPS);
  a1s[c] = a;
  c1s[c] = fmaf(-(float)m, a, be1[c]);
  __syncthreads();
  float acc = b2[c];
  for (int k = 0; k < 64; ++k) acc = fmaf(c1s[k], W2[k * 64 + c], acc);
  b2sh[c] = acc;
  const int lg = c >> 4, l15 = c & 15;
#pragma unroll
  for (int t = 0; t < 4; ++t)
#pragma unroll
    for (int s = 0; s < 2; ++s)
#pragma unroll
      for (int i = 0; i < 8; ++i) {
        const int k = s * 32 + lg * 8 + i;
        bFpack[c * 64 + t * 16 + s * 8 + i] = f2bf(a1s[k] * W2[k * 64 + l15 + 16 * t]);
      }
  __syncthreads();
  float4 bf;
  bf.x = b2sh[l15]; bf.y = b2sh[l15 + 16]; bf.z = b2sh[l15 + 32]; bf.w = b2sh[l15 + 48];
  ((float4*)biasF)[c] = bf;
}

// ---- edge pass 2 (node-centric, zero atomics) + fused raw-max stats:
//      wave owns node d; MFMA over its rows; masked t2-stats; in-register max;
//      one plain 256B store; accumulates BNf stats (sum/sq of maxima + count) ----
__global__ __launch_bounds__(256) void k_edge2(
    const unsigned short* __restrict__ t1S, const unsigned int* __restrict__ cursor0,
    const unsigned short* __restrict__ bFpack, const float* __restrict__ biasF,
    long long* __restrict__ stats, float* __restrict__ agg, int N) {
  const int tid = threadIdx.x, lane = tid & 63, wv = tid >> 6;
  const int l15 = lane & 15, lg = lane >> 4;
  s16x8 bF[4][2];
  {
    const s16x8* bfp = (const s16x8*)(bFpack + (size_t)lane * 64);
#pragma unroll
    for (int t = 0; t < 4; ++t)
#pragma unroll
      for (int s = 0; s < 2; ++s) bF[t][s] = bfp[t * 2 + s];
  }
  float bias[4];
  {
    const float4 bv = ((const float4*)biasF)[lane];
    bias[0] = bv.x; bias[1] = bv.y; bias[2] = bv.z; bias[3] = bv.w;
  }
  float ssum[4] = {0.f, 0.f, 0.f, 0.f}, ssq[4] = {0.f, 0.f, 0.f, 0.f};
  float msum[4] = {0.f, 0.f, 0.f, 0.f}, msq[4] = {0.f, 0.f, 0.f, 0.f};
  float kc = 0.f;
  const int nw = gridDim.x * 4;
  for (int d = blockIdx.x * 4 + wv; d < N; d += nw) {
    const unsigned lo = cursor0[d];
    const unsigned deg = cursor0[d + 1] - lo;
    if (deg == 0) continue;  // wave-uniform; agg never read for empty nodes
    kc += 1.f;
    const unsigned last = lo + deg - 1u;
    float mx[4] = {0.f, 0.f, 0.f, 0.f};
    for (unsigned base = 0; base < deg; base += 16u) {
      unsigned gr = lo + base + (unsigned)l15;
      if (gr > last) gr = last;  // clamp: duplicates of a real row (max-safe)
      const unsigned short* ar = t1S + (size_t)gr * 64 + (unsigned)(lg * 8);
      const s16x8 aF0 = *(const s16x8*)ar;
      const s16x8 aF1 = *(const s16x8*)(ar + 32);
      fx4 acc[4];
#pragma unroll
      for (int t = 0; t < 4; ++t) {
        acc[t][0] = bias[t]; acc[t][1] = bias[t];
        acc[t][2] = bias[t]; acc[t][3] = bias[t];
      }
#pragma unroll
      for (int t = 0; t < 4; ++t) {
        acc[t] = __builtin_amdgcn_mfma_f32_16x16x32_bf16(aF0, bF[t][0], acc[t], 0, 0, 0);
        acc[t] = __builtin_amdgcn_mfma_f32_16x16x32_bf16(aF1, bF[t][1], acc[t], 0, 0, 0);
      }
      const int rem = (int)(deg - base);  // valid rows this tile (may exceed 16)
#pragma unroll
      for (int t = 0; t < 4; ++t)
#pragma unroll
        for (int j = 0; j < 4; ++j) {
          const float v = fmaxf(acc[t][j], 0.f);
          mx[t] = fmaxf(mx[t], v);  // duplicate rows repeat a real value: safe
          const int row = lg * 4 + j;
          if (row < rem) {  // masked stats: each edge row counted exactly once
            ssum[t] += v;
            ssq[t] = fmaf(v, v, ssq[t]);
          }
        }
    }
#pragma unroll
    for (int t = 0; t < 4; ++t) {
      mx[t] = fmaxf(mx[t], __shfl_xor(mx[t], 16));
      mx[t] = fmaxf(mx[t], __shfl_xor(mx[t], 32));
    }
    // fused BNf raw-max stats: mx[t] identical across lg; count each channel once
    if (lg == 0) {
#pragma unroll
      for (int t = 0; t < 4; ++t) {
        msum[t] += mx[t];
        msq[t] = fmaf(mx[t], mx[t], msq[t]);
      }
    }
    const float val = (lg == 0) ? mx[0] : (lg == 1) ? mx[1] : (lg == 2) ? mx[2] : mx[3];
    agg[(size_t)d * 64 + (unsigned)(l15 + 16 * lg)] = val;  // plain coalesced store
  }
#pragma unroll
  for (int t = 0; t < 4; ++t) {
    ssum[t] += __shfl_xor(ssum[t], 16); ssum[t] += __shfl_xor(ssum[t], 32);
    ssq[t]  += __shfl_xor(ssq[t], 16);  ssq[t]  += __shfl_xor(ssq[t], 32);
  }
  __shared__ float sred[4][64];
  __shared__ float kcs;
  if (tid < 256) ((float*)sred)[tid] = 0.f;
  if (tid == 0) kcs = 0.f;
  __syncthreads();
  if (lg == 0) {
#pragma unroll
    for (int t = 0; t < 4; ++t) {
      atomicAdd(&sred[0][l15 + 16 * t], ssum[t]);
      atomicAdd(&sred[1][l15 + 16 * t], ssq[t]);
      atomicAdd(&sred[2][l15 + 16 * t], msum[t]);
      atomicAdd(&sred[3][l15 + 16 * t], msq[t]);
    }
  }
  if (lane == 0) atomicAdd(&kcs, kc);
  __syncthreads();
  if (tid < 64) {
    atomicAdd((unsigned long long*)&stats[128 + tid],
              (unsigned long long)(long long)((double)sred[0][tid] * SCALE));
    atomicAdd((unsigned long long*)&stats[192 + tid],
              (unsigned long long)(long long)((double)sred[1][tid] * SCALE));
    atomicAdd((unsigned long long*)&stats[384 + tid],
              (unsigned long long)(long long)((double)sred[2][tid] * SCALE));
    atomicAdd((unsigned long long*)&stats[448 + tid],
              (unsigned long long)(long long)((double)sred[3][tid] * SCALE));
  }
  if (tid == 0)
    atomicAdd((unsigned long long*)&stats[512],
              (unsigned long long)(long long)((double)kcs * SCALE));
}

// ---- remaining BN coefs composed for the final pass ----
__global__ void k_coefB(const long long* __restrict__ stats,
                        const float* __restrict__ g2, const float* __restrict__ be2,
                        const float* __restrict__ gs, const float* __restrict__ bes,
                        const float* __restrict__ gf, const float* __restrict__ bef,
                        float* __restrict__ coef, double invE, double invN, int N) {
  const int c = threadIdx.x;
  double m2 = (double)stats[128 + c] * invE;
  double v2 = (double)stats[192 + c] * invE - m2 * m2;
  float a2 = g2[c] * rsqrtf((float)v2 + EPS);
  float c2 = fmaf(-(float)m2, a2, be2[c]);
  double mS = (double)stats[256 + c] * invN;
  double vS = (double)stats[320 + c] * invN - mS * mS;
  float aS = gs[c] * rsqrtf((float)vS + EPS);
  float cS = fmaf(-(float)mS, aS, bes[c]);
  double su = (double)stats[384 + c] / SCALE;
  double qu = (double)stats[448 + c] / SCALE;
  double K  = (double)stats[512] / SCALE;
  double sv = (double)a2 * su + (double)c2 * K;
  double qv = (double)a2 * a2 * qu + 2.0 * a2 * c2 * su + (double)c2 * c2 * K;
  double mv = sv / N;
  double vv = qv / N - mv * mv;
  float aF = gf[c] * rsqrtf((float)vv + EPS);
  float cF = fmaf(-(float)mv, aF, bef[c]);
  coef[c]       = aF * a2;
  coef[64 + c]  = fmaf(aF, c2, cF);
  coef[128 + c] = cF;
  coef[192 + c] = aS;
  coef[256 + c] = cS;
}

__global__ __launch_bounds__(256) void k_final(
    const float* __restrict__ agg, const unsigned int* __restrict__ hist,
    const unsigned short* __restrict__ sbuf, const float* __restrict__ coef,
    float* __restrict__ out, int total) {
  int i = blockIdx.x * 256 + threadIdx.x;
  if (i >= total) return;
  const int c = i & 63;
  float base;
  if (hist[i >> 6])
    base = fmaf(coef[c], agg[i], coef[64 + c]);
  else
    base = coef[128 + c];
  const float sv = fmaf(coef[192 + c], bf2f(sbuf[i]), coef[256 + c]);
  out[i] = fmaxf(base + sv, 0.f);
}

extern "C" void kernel_launch(void* const* d_in, const int* in_sizes, int n_in,
                              void* d_out, int out_size, void* d_ws, size_t ws_size,
                              hipStream_t stream) {
  const float* x   = (const float*)d_in[0];
  const float* pos = (const float*)d_in[1];
  const int*   ei  = (const int*)d_in[2];
  const float* W1  = (const float*)d_in[3];
  const float* b1  = (const float*)d_in[4];
  const float* g1  = (const float*)d_in[5];
  const float* be1 = (const float*)d_in[6];
  const float* W2  = (const float*)d_in[7];
  const float* b2  = (const float*)d_in[8];
  const float* g2  = (const float*)d_in[9];
  const float* be2 = (const float*)d_in[10];
  const float* Ws  = (const float*)d_in[11];
  const float* bs  = (const float*)d_in[12];
  const float* gs  = (const float*)d_in[13];
  const float* bes = (const float*)d_in[14];
  const float* gf  = (const float*)d_in[15];
  const float* bef = (const float*)d_in[16];
  const int N = in_sizes[0] / CIN;   // 50000
  const int E = in_sizes[2] / 2;     // 800000

  char* ws = (char*)d_ws;
  const size_t o_stats = 0;                            // 513 ll -> pad 4608
  const size_t o_bsum  = 4608;                         // 49 u32 -> page ends 8192
  const size_t o_hist  = 8192;                         // 50176 u32 (zeroed)
  const size_t zeroEnd = o_hist + 200704;              // memset ONLY stats+hist
  const size_t o_agg   = zeroEnd;                      // N*256 (f32; no init needed)
  const size_t o_curs0 = o_agg + (size_t)N * 256;      // 50176 u32
  const size_t o_coef  = o_curs0 + 200704;             // 4096
  const size_t o_frag  = o_coef + 4096;                // bFpack 8192 | biasF 1024
  const size_t o_rank  = o_frag + 12288;               // E*2
  const size_t o_ybuf  = o_rank + (size_t)E * 2;       // N*128
  const size_t o_sbuf  = o_ybuf + (size_t)N * 128;     // N*128
  const size_t o_t1S   = o_sbuf + (size_t)N * 128;     // E*128

  long long* stats      = (long long*)(ws + o_stats);
  unsigned int* bsum    = (unsigned int*)(ws + o_bsum);
  unsigned int* hist    = (unsigned int*)(ws + o_hist);
  float* agg            = (float*)(ws + o_agg);
  unsigned int* cursor0 = (unsigned int*)(ws + o_curs0);
  float* coef           = (float*)(ws + o_coef);
  unsigned short* bFpack= (unsigned short*)(ws + o_frag);
  float* biasF          = (float*)(ws + o_frag + 8192);
  unsigned short* rank  = (unsigned short*)(ws + o_rank);
  unsigned short* ybuf  = (unsigned short*)(ws + o_ybuf);
  unsigned short* sbuf  = (unsigned short*)(ws + o_sbuf);
  unsigned short* t1S   = (unsigned short*)(ws + o_t1S);

  const double invE = 1.0 / (SCALE * (double)E);
  const double invN = 1.0 / (SCALE * (double)N);
  const int total = N * 64;
  const int nScanBlk = 49;  // ceil(50176/1024)

  hipMemsetAsync(d_ws, 0, zeroEnd, stream);

  hipLaunchKernelGGL(k_node, dim3(1024), dim3(256), 0, stream,
                     x, W1, b1, Ws, bs, ybuf, sbuf, stats, N, ei, hist, rank, E, 448);
  hipLaunchKernelGGL(k_scan1, dim3(nScanBlk), dim3(256), 0, stream, hist, bsum);
  hipLaunchKernelGGL(k_scan3, dim3(nScanBlk), dim3(256), 0, stream,
                     hist, bsum, cursor0);
  hipLaunchKernelGGL(k_edge1, dim3(2048), dim3(256), 0, stream,
                     ei, pos, ybuf, W1, cursor0, rank, t1S, stats, E);
  hipLaunchKernelGGL(k_coefA, dim3(1), dim3(64), 0, stream,
                     stats, g1, be1, W2, b2, bFpack, biasF, invE);
  hipLaunchKernelGGL(k_edge2, dim3(2048), dim3(256), 0, stream,
                     t1S, cursor0, bFpack, biasF, stats, agg, N);
  hipLaunchKernelGGL(k_coefB, dim3(1), dim3(64), 0, stream,
                     stats, g2, be2, gs, bes, gf, bef, coef, invE, invN, N);
  hipLaunchKernelGGL(k_final, dim3((total + 255) / 256), dim3(256), 0, stream,
                     agg, hist, sbuf, coef, (float*)d_out, total);
}